// Round 6
// baseline (436.911 us; speedup 1.0000x reference)
//
#include <hip/hip_runtime.h>
#include <hip/hip_bf16.h>

typedef __bf16 bf16_t;
typedef __bf16 bf16x4 __attribute__((ext_vector_type(4)));
typedef __bf16 bf16x8 __attribute__((ext_vector_type(8)));
typedef float f32x4 __attribute__((ext_vector_type(4)));
typedef float f32x16 __attribute__((ext_vector_type(16)));

#define LN_EPS 1e-6f

__device__ __forceinline__ void gl2lds16(const void* g, void* l) {
    __builtin_amdgcn_global_load_lds(
        (const __attribute__((address_space(1))) void*)g,
        (__attribute__((address_space(3))) void*)l, 16, 0, 0);
}

// ---------------- transpose + fp32->bf16 convert (Wo only: [K,N] -> [N,K]) ----------------
__global__ void transpose_cvt_kernel(const float* __restrict__ in, bf16_t* __restrict__ out,
                                     int R, int C) {
    __shared__ float tile[32][33];
    int tx = threadIdx.x & 31;
    int ty = threadIdx.x >> 5;
    int r0 = blockIdx.y * 32;
    int c0 = blockIdx.x * 32;
#pragma unroll
    for (int i = 0; i < 4; i++) {
        int r = ty + i * 8;
        tile[r][tx] = in[(size_t)(r0 + r) * C + (c0 + tx)];
    }
    __syncthreads();
#pragma unroll
    for (int i = 0; i < 4; i++) {
        int r = ty + i * 8;
        out[(size_t)(c0 + r) * R + (r0 + tx)] = (bf16_t)tile[tx][r];
    }
}

// ---------------- k-interleave + fp32->bf16: W [K,Nw] -> Bw [(K/8)][N_out][8] ----------------
// mode 0: out_n = n + noff ; mode 1 (w1/w3 pairing): out_n = (n>>5)*64 + (n&31) + noff
__global__ void interleave_cvt_kernel(const float* __restrict__ in, bf16_t* __restrict__ out,
                                      int K, int Nw, int N_out, int noff, int mode) {
    __shared__ bf16_t tile[32][72];
    int t = threadIdx.x;
    int k0 = blockIdx.y * 32, n0 = blockIdx.x * 64;
    int c = t & 63;
#pragma unroll
    for (int i = 0; i < 8; i++) {
        int r = (t >> 6) + i * 4;
        tile[r][c] = (bf16_t)in[(size_t)(k0 + r) * Nw + n0 + c];
    }
    __syncthreads();
    int kg = t >> 6;  // 0..3
    int n = t & 63;
    bf16x8 v;
#pragma unroll
    for (int j = 0; j < 8; j++) v[j] = tile[kg * 8 + j][n];
    int gn = n0 + n;
    int out_n = (mode == 1) ? ((gn >> 5) * 64 + (gn & 31) + noff) : (gn + noff);
    *reinterpret_cast<bf16x8*>(out + ((size_t)(k0 >> 3) + kg) * N_out * 8 + (size_t)out_n * 8) = v;
}

// ---------------- LayerNorm (fp32 in) -> bf16 out ----------------
__global__ void ln_kernel(const float* __restrict__ x, const float* __restrict__ g,
                          const float* __restrict__ bb, bf16_t* __restrict__ out, int D) {
    int row = blockIdx.x;
    int t = threadIdx.x;
    const float4* xr = reinterpret_cast<const float4*>(x + (size_t)row * D);
    float4 v = xr[t];
    float s = v.x + v.y + v.z + v.w;
    __shared__ float sbuf[4];
    __shared__ float sbuf2[4];
    int wave = t >> 6, lane = t & 63;
#pragma unroll
    for (int o = 32; o > 0; o >>= 1) s += __shfl_xor(s, o);
    if (lane == 0) sbuf[wave] = s;
    __syncthreads();
    float mean = (sbuf[0] + sbuf[1] + sbuf[2] + sbuf[3]) / (float)D;
    float d0 = v.x - mean, d1 = v.y - mean, d2 = v.z - mean, d3 = v.w - mean;
    float sq = d0 * d0 + d1 * d1 + d2 * d2 + d3 * d3;
#pragma unroll
    for (int o = 32; o > 0; o >>= 1) sq += __shfl_xor(sq, o);
    if (lane == 0) sbuf2[wave] = sq;
    __syncthreads();
    float var = (sbuf2[0] + sbuf2[1] + sbuf2[2] + sbuf2[3]) / (float)D;
    float inv = rsqrtf(var + LN_EPS);
    float4 gv = reinterpret_cast<const float4*>(g)[t];
    float4 bv = reinterpret_cast<const float4*>(bb)[t];
    bf16_t* o0 = out + (size_t)row * D + t * 4;
    o0[0] = (bf16_t)(d0 * inv * gv.x + bv.x);
    o0[1] = (bf16_t)(d1 * inv * gv.y + bv.y);
    o0[2] = (bf16_t)(d2 * inv * gv.z + bv.z);
    o0[3] = (bf16_t)(d3 * inv * gv.w + bv.w);
}

// ---------------- 16x16 MFMA GEMM (Wo): Cf = acc + aux ----------------
#define BM 128
#define BN 128
#define BKK 32

__launch_bounds__(256, 2) __global__
void gemm_kernel(const bf16_t* __restrict__ A, const bf16_t* __restrict__ Bt,
                 float* __restrict__ Cf, const float* __restrict__ aux,
                 int M, int N, int K) {
    __shared__ __align__(16) bf16_t As[BM * BKK];
    __shared__ __align__(16) bf16_t Bs[BN * BKK];
    int t = threadIdx.x;
    int lin = blockIdx.y * gridDim.x + blockIdx.x;
    int gmt = gridDim.y;
    int gw = 8 * gmt;
    int grp = lin / gw;
    int rem = lin - grp * gw;
    int bn = grp * 8 + (rem & 7);
    int bm = rem >> 3;
    int m0 = bm * BM;
    int n0 = bn * BN;
    int wave = t >> 6, lane = t & 63;
    int wm = (wave >> 1) * 64, wn = (wave & 1) * 64;
    int lr = lane & 15;
    int quad = lane >> 4;

    int srow = lane >> 2;
    int scol = (lane & 3) * 8;
    const bf16_t* ag = A + (size_t)(m0 + wave * 16 + srow) * K + scol;
    const bf16_t* bg = Bt + (size_t)(n0 + wave * 16 + srow) * K + scol;
    bf16_t* asl = As + wave * 16 * BKK;
    bf16_t* bsl = Bs + wave * 16 * BKK;
    const size_t rowskip = (size_t)64 * K;

    f32x4 acc[4][4];
#pragma unroll
    for (int mi = 0; mi < 4; mi++)
#pragma unroll
        for (int ni = 0; ni < 4; ni++) acc[mi][ni] = 0.f;

    for (int k0 = 0; k0 < K; k0 += BKK) {
        gl2lds16(ag + k0, asl);
        gl2lds16(ag + k0 + rowskip, asl + 64 * BKK);
        gl2lds16(bg + k0, bsl);
        gl2lds16(bg + k0 + rowskip, bsl + 64 * BKK);
        __syncthreads();
        bf16x8 af[4], bfv[4];
#pragma unroll
        for (int mi = 0; mi < 4; mi++)
            af[mi] = *reinterpret_cast<const bf16x8*>(&As[(wm + mi * 16 + lr) * BKK + quad * 8]);
#pragma unroll
        for (int ni = 0; ni < 4; ni++)
            bfv[ni] = *reinterpret_cast<const bf16x8*>(&Bs[(wn + ni * 16 + lr) * BKK + quad * 8]);
#pragma unroll
        for (int mi = 0; mi < 4; mi++)
#pragma unroll
            for (int ni = 0; ni < 4; ni++)
                acc[mi][ni] = __builtin_amdgcn_mfma_f32_16x16x32_bf16(af[mi], bfv[ni],
                                                                      acc[mi][ni], 0, 0, 0);
        __syncthreads();
    }
#pragma unroll
    for (int mi = 0; mi < 4; mi++)
#pragma unroll
        for (int ni = 0; ni < 4; ni++)
#pragma unroll
            for (int j = 0; j < 4; j++) {
                int gm = m0 + wm + mi * 16 + quad * 4 + j;
                int gn = n0 + wn + ni * 16 + lr;
                size_t idx = (size_t)gm * N + gn;
                Cf[idx] = acc[mi][ni][j] + aux[idx];
            }
}

// ---------------- 32x32 MFMA GEMM v2: A via LDS, B direct-global (k-interleaved) ----------
// A [M, lda] row-major bf16; Bw [(Ktot/8)][N][8] bf16. grid (M/256, N/128, zK).
// EPI 3: QKV fused RoPE (N=3072; cols<2048 rope, else plain)
// EPI 5: split-K partial:  Cb[z*M*N + gm*N + gn] = acc (bf16)
// EPI 6: paired w1/w3 SwiGLU: ni even = w1, ni odd = w3; Cb[gm*(N/2) + n0/2 + p*32 + col]
#define G2_BM 256
#define G2_BN 128
#define G2_BK 32

template <int EPI>
__launch_bounds__(256, 2) __global__
void gemm2_kernel(const bf16_t* __restrict__ A, const bf16_t* __restrict__ Bw,
                  bf16_t* __restrict__ Cb, int M, int N, int K, int lda) {
    __shared__ __align__(16) bf16_t As[G2_BM * G2_BK];  // 16 KB
    int t = threadIdx.x;
    int wave = t >> 6, lane = t & 63;
    int m0 = blockIdx.x * G2_BM;
    int n0 = blockIdx.y * G2_BN;
    int koff = blockIdx.z * K;

    // A staging: wave stages rows [64w, 64w+64) in 4 DMA chunks of 16 rows.
    // LDS slot (r, c) holds global k-quad c ^ ((r>>1)&3)  [4-way-spread swizzle]
    int sr = lane >> 2;
    int sc = lane & 3;
    int sq = sc ^ ((sr >> 1) & 3);
    const bf16_t* ag = A + (size_t)(m0 + 64 * wave + sr) * lda + koff + sq * 8;
    bf16_t* asl = As + (64 * wave) * G2_BK;

    f32x16 acc[2][4];
#pragma unroll
    for (int mi = 0; mi < 2; mi++)
#pragma unroll
        for (int ni = 0; ni < 4; ni++) acc[mi][ni] = 0.f;

    int l31 = lane & 31;
    int lh = lane >> 5;
    int rsw = (l31 >> 1) & 3;

    for (int k0 = 0; k0 < K; k0 += G2_BK) {
#pragma unroll
        for (int i = 0; i < 4; i++)
            gl2lds16(ag + k0 + (size_t)(16 * i) * lda, asl + (16 * i) * G2_BK);
        __syncthreads();
        bf16x8 bfv[2][4], af[2][2];
#pragma unroll
        for (int s = 0; s < 2; s++) {
            int q = 2 * s + lh;
            size_t qrow = ((size_t)((koff + k0) >> 3) + q) * N * 8;
#pragma unroll
            for (int ni = 0; ni < 4; ni++)
                bfv[s][ni] = *reinterpret_cast<const bf16x8*>(
                    Bw + qrow + (size_t)(n0 + ni * 32 + l31) * 8);
#pragma unroll
            for (int mi = 0; mi < 2; mi++)
                af[s][mi] = *reinterpret_cast<const bf16x8*>(
                    &As[(64 * wave + mi * 32 + l31) * G2_BK + ((q ^ rsw) << 3)]);
        }
#pragma unroll
        for (int s = 0; s < 2; s++)
#pragma unroll
            for (int mi = 0; mi < 2; mi++)
#pragma unroll
                for (int ni = 0; ni < 4; ni++)
                    acc[mi][ni] = __builtin_amdgcn_mfma_f32_32x32x16_bf16(
                        af[s][mi], bfv[s][ni], acc[mi][ni], 0, 0, 0);
        __syncthreads();
    }

    // C/D layout: col = lane&31, row = (reg&3) + 8*(reg>>2) + 4*(lane>>5)
    if constexpr (EPI == 3) {
        const float kfreq = -0.41524101186f;  // -log2(10000)/32
        bool do_rope = (n0 < 2048);
#pragma unroll
        for (int mi = 0; mi < 2; mi++) {
#pragma unroll
            for (int reg = 0; reg < 16; reg++) {
                int rrow = (reg & 3) + 8 * (reg >> 2) + 4 * lh;
                int gm = m0 + 64 * wave + mi * 32 + rrow;
                if (do_rope) {
                    float sf = (float)(gm & 2047);
                    float freq = exp2f((float)l31 * kfreq);
                    float ang = sf * freq;
                    float sn, cs;
                    __sincosf(ang, &sn, &cs);
#pragma unroll
                    for (int p = 0; p < 2; p++) {
                        float x1 = acc[mi][2 * p][reg];
                        float x2 = acc[mi][2 * p + 1][reg];
                        size_t idx = (size_t)gm * N + n0 + p * 64 + l31;
                        Cb[idx] = (bf16_t)(x1 * cs - x2 * sn);
                        Cb[idx + 32] = (bf16_t)(x2 * cs + x1 * sn);
                    }
                } else {
#pragma unroll
                    for (int ni = 0; ni < 4; ni++) {
                        size_t idx = (size_t)gm * N + n0 + ni * 32 + l31;
                        Cb[idx] = (bf16_t)acc[mi][ni][reg];
                    }
                }
            }
        }
    } else if constexpr (EPI == 6) {
        int ldc = N >> 1;
#pragma unroll
        for (int mi = 0; mi < 2; mi++) {
#pragma unroll
            for (int reg = 0; reg < 16; reg++) {
                int rrow = (reg & 3) + 8 * (reg >> 2) + 4 * lh;
                int gm = m0 + 64 * wave + mi * 32 + rrow;
#pragma unroll
                for (int p = 0; p < 2; p++) {
                    float a1 = acc[mi][2 * p][reg];
                    float a3 = acc[mi][2 * p + 1][reg];
                    float sl = a1 / (1.0f + __expf(-a1));
                    Cb[(size_t)gm * ldc + (n0 >> 1) + p * 32 + l31] = (bf16_t)(sl * a3);
                }
            }
        }
    } else {  // EPI 5
        size_t outoff = (size_t)blockIdx.z * M * N;
#pragma unroll
        for (int mi = 0; mi < 2; mi++) {
#pragma unroll
            for (int reg = 0; reg < 16; reg++) {
                int rrow = (reg & 3) + 8 * (reg >> 2) + 4 * lh;
                int gm = m0 + 64 * wave + mi * 32 + rrow;
#pragma unroll
                for (int ni = 0; ni < 4; ni++)
                    Cb[outoff + (size_t)gm * N + n0 + ni * 32 + l31] = (bf16_t)acc[mi][ni][reg];
            }
        }
    }
}

// ---------------- split-K reduce + residual: out = hid + sum_c partial[c] ----------------
__global__ void reduce4_kernel(const bf16_t* __restrict__ p, const float* __restrict__ hid,
                               float* __restrict__ out, int n4) {
    int i = blockIdx.x * 256 + threadIdx.x;
    if (i >= n4) return;
    size_t i4 = (size_t)i * 4;
    float4 h = *reinterpret_cast<const float4*>(hid + i4);
    const size_t stride = (size_t)4096 * 1024;
#pragma unroll
    for (int c = 0; c < 4; c++) {
        bf16x4 a = *reinterpret_cast<const bf16x4*>(p + c * stride + i4);
        h.x += (float)a[0];
        h.y += (float)a[1];
        h.z += (float)a[2];
        h.w += (float)a[3];
    }
    *reinterpret_cast<float4*>(out + i4) = h;
}

// ---------------- V transpose: qkv v-section [B*S, 3072] -> vt [B, H, 64, S] ----------------
__global__ void transpose_v_kernel(const bf16_t* __restrict__ v, bf16_t* __restrict__ vt,
                                   int S, int stride) {
    __shared__ bf16_t tile[64][66];
    int t = threadIdx.x;
    int s0 = blockIdx.x * 64;
    int h = blockIdx.y, b = blockIdx.z;
#pragma unroll
    for (int i = 0; i < 2; i++) {
        int c = t + i * 256;
        int ss = c >> 3, d8 = (c & 7) * 8;
        bf16x8 val = *reinterpret_cast<const bf16x8*>(
            &v[(size_t)(b * S + s0 + ss) * stride + h * 64 + d8]);
#pragma unroll
        for (int jj = 0; jj < 8; jj++) tile[ss][d8 + jj] = val[jj];
    }
    __syncthreads();
#pragma unroll
    for (int i = 0; i < 2; i++) {
        int c = t + i * 256;
        int d = c >> 3, s8 = (c & 7) * 8;
        bf16x8 o;
#pragma unroll
        for (int jj = 0; jj < 8; jj++) o[jj] = tile[s8 + jj][d];
        *reinterpret_cast<bf16x8*>(&vt[(((size_t)(b * 16 + h)) * 64 + d) * S + s0 + s8]) = o;
    }
}

// ---------------- MFMA sliding-window attention ----------------
#define PSTR 40
#define QKVS 3072
__global__ __launch_bounds__(256, 2) void attn_kernel(const bf16_t* __restrict__ qkv,
                                                      const bf16_t* __restrict__ vt,
                                                      bf16_t* __restrict__ ctx, int S) {
    __shared__ __align__(16) bf16_t Pbuf[4][16 * PSTR];
    int t = threadIdx.x;
    int wave = t >> 6, lane = t & 63;
    int col = lane & 15, quad = lane >> 4;
    int h = blockIdx.y, b = blockIdx.z;
    int q0 = blockIdx.x * 64 + wave * 16;

    const bf16_t* qrow = qkv + (size_t)(b * S + q0 + col) * QKVS + h * 64;
    bf16x8 aq0 = *reinterpret_cast<const bf16x8*>(qrow + quad * 8);
    bf16x8 aq1 = *reinterpret_cast<const bf16x8*>(qrow + 32 + quad * 8);

    int jbase = q0 - 256;
    f32x4 sc[18];
#pragma unroll
    for (int kt = 0; kt < 18; kt++) {
        int j = jbase + kt * 16 + col;
        int jc = j < 0 ? 0 : (j > S - 1 ? S - 1 : j);
        const bf16_t* krow = qkv + (size_t)(b * S + jc) * QKVS + 1024 + h * 64;
        bf16x8 bk0 = *reinterpret_cast<const bf16x8*>(krow + quad * 8);
        bf16x8 bk1 = *reinterpret_cast<const bf16x8*>(krow + 32 + quad * 8);
        f32x4 c0 = {0.f, 0.f, 0.f, 0.f};
        c0 = __builtin_amdgcn_mfma_f32_16x16x32_bf16(aq0, bk0, c0, 0, 0, 0);
        c0 = __builtin_amdgcn_mfma_f32_16x16x32_bf16(aq1, bk1, c0, 0, 0, 0);
        sc[kt] = c0;
    }
#pragma unroll
    for (int kt = 0; kt < 18; kt++) {
#pragma unroll
        for (int jj = 0; jj < 4; jj++) {
            int qq = quad * 4 + jj;
            int j = jbase + kt * 16 + col;
            int rel = (q0 + qq) - j;
            bool ok = (j >= 0) && (rel >= 0) && (rel < 256);
            sc[kt][jj] = ok ? sc[kt][jj] * 0.125f : -1e30f;
        }
    }
    float sminv[4];
#pragma unroll
    for (int jj = 0; jj < 4; jj++) {
        float m = -1e30f;
#pragma unroll
        for (int kt = 0; kt < 18; kt++) m = fmaxf(m, sc[kt][jj]);
#pragma unroll
        for (int o = 1; o < 16; o <<= 1) m = fmaxf(m, __shfl_xor(m, o));
        float s = 0.f;
#pragma unroll
        for (int kt = 0; kt < 18; kt++) {
            float p = __expf(sc[kt][jj] - m);
            sc[kt][jj] = p;
            s += p;
        }
#pragma unroll
        for (int o = 1; o < 16; o <<= 1) s += __shfl_xor(s, o);
        sminv[jj] = 1.0f / s;
    }
    f32x4 o[4];
#pragma unroll
    for (int n = 0; n < 4; n++) o[n] = 0.f;
    bf16_t* myP = Pbuf[wave];
    const bf16_t* vplane = vt + ((size_t)(b * 16 + h)) * 64 * S;
#pragma unroll
    for (int c = 0; c < 9; c++) {
#pragma unroll
        for (int half = 0; half < 2; half++) {
            int kt = 2 * c + half;
#pragma unroll
            for (int jj = 0; jj < 4; jj++) {
                int qq = quad * 4 + jj;
                myP[qq * PSTR + half * 16 + col] = (bf16_t)(sc[kt][jj] * sminv[jj]);
            }
        }
        bf16x8 ap = *reinterpret_cast<const bf16x8*>(myP + col * PSTR + quad * 8);
        int key0 = jbase + c * 32 + quad * 8;
        int kc = key0 < 0 ? 0 : (key0 > S - 8 ? S - 8 : key0);
#pragma unroll
        for (int n = 0; n < 4; n++) {
            bf16x8 bv = *reinterpret_cast<const bf16x8*>(vplane + ((size_t)(n * 16 + col)) * S + kc);
            o[n] = __builtin_amdgcn_mfma_f32_16x16x32_bf16(ap, bv, o[n], 0, 0, 0);
        }
    }
#pragma unroll
    for (int n = 0; n < 4; n++)
#pragma unroll
        for (int jj = 0; jj < 4; jj++) {
            int qq = quad * 4 + jj;
            ctx[((size_t)(b * S + q0 + qq) * 16 + h) * 64 + n * 16 + col] = (bf16_t)o[n][jj];
        }
}

// ---------------- launch ----------------
extern "C" void kernel_launch(void* const* d_in, const int* in_sizes, int n_in,
                              void* d_out, int out_size, void* d_ws, size_t ws_size,
                              hipStream_t stream) {
    const float* hs   = (const float*)d_in[0];
    const float* wq   = (const float*)d_in[1];
    const float* wk   = (const float*)d_in[2];
    const float* wv   = (const float*)d_in[3];
    const float* wo   = (const float*)d_in[4];
    const float* w1   = (const float*)d_in[5];
    const float* w2   = (const float*)d_in[6];
    const float* w3   = (const float*)d_in[7];
    const float* ln1g = (const float*)d_in[8];
    const float* ln1b = (const float*)d_in[9];
    const float* ln2g = (const float*)d_in[10];
    const float* ln2b = (const float*)d_in[11];
    float* out = (float*)d_out;

    const int B = 2, S = 2048, D = 1024, I = 4096;
    const int BS = B * S;

    char* ws = (char*)d_ws;
    const size_t MB = 1024 * 1024;
    bf16_t* wo_t  = (bf16_t*)(ws + 0 * MB);    // 2MB [N,K]
    bf16_t* qkvw  = (bf16_t*)(ws + 2 * MB);    // 6MB [128][3072][8]
    bf16_t* w13w  = (bf16_t*)(ws + 8 * MB);    // 16MB [128][8192][8] (w1/w3 col-paired)
    bf16_t* w2w   = (bf16_t*)(ws + 24 * MB);   // 8MB [512][1024][8]
    bf16_t* x_b   = (bf16_t*)(ws + 32 * MB);   // 8MB
    float*  hid   = (float*)(ws + 40 * MB);    // 16MB
    bf16_t* x2_b  = (bf16_t*)(ws + 56 * MB);   // 8MB
    bf16_t* qkvb  = (bf16_t*)(ws + 64 * MB);   // 24MB [BS,3072]
    bf16_t* vt    = (bf16_t*)(ws + 88 * MB);   // 8MB
    bf16_t* ctxb  = (bf16_t*)(ws + 96 * MB);   // 8MB
    bf16_t* hbuf  = (bf16_t*)(ws + 64 * MB);   // 32MB [BS,4096], aliases qkvb+vt (dead post-attn)
    bf16_t* pker  = (bf16_t*)(ws + 96 * MB);   // 32MB, aliases ctxb (dead post-Wo); end 128MB

    dim3 tb(256);
    transpose_cvt_kernel<<<dim3(D / 32, D / 32), tb, 0, stream>>>(wo, wo_t, D, D);
    interleave_cvt_kernel<<<dim3(D / 64, D / 32), tb, 0, stream>>>(wq, qkvw, D, D, 3072, 0, 0);
    interleave_cvt_kernel<<<dim3(D / 64, D / 32), tb, 0, stream>>>(wk, qkvw, D, D, 3072, 1024, 0);
    interleave_cvt_kernel<<<dim3(D / 64, D / 32), tb, 0, stream>>>(wv, qkvw, D, D, 3072, 2048, 0);
    interleave_cvt_kernel<<<dim3(I / 64, D / 32), tb, 0, stream>>>(w1, w13w, D, I, 8192, 0, 1);
    interleave_cvt_kernel<<<dim3(I / 64, D / 32), tb, 0, stream>>>(w3, w13w, D, I, 8192, 32, 1);
    interleave_cvt_kernel<<<dim3(D / 64, I / 32), tb, 0, stream>>>(w2, w2w, I, D, 1024, 0, 0);

    ln_kernel<<<BS, tb, 0, stream>>>(hs, ln1g, ln1b, x_b, D);

    // fused QKV GEMM (RoPE in epilogue), B direct-global k-interleaved
    gemm2_kernel<3><<<dim3(BS / G2_BM, 3072 / G2_BN), tb, 0, stream>>>(
        x_b, qkvw, qkvb, BS, 3072, D, D);

    transpose_v_kernel<<<dim3(S / 64, 16, B), tb, 0, stream>>>(qkvb + 2048, vt, S, QKVS);

    attn_kernel<<<dim3(S / 64, 16, B), tb, 0, stream>>>(qkvb, vt, ctxb, S);

    gemm_kernel<<<dim3(D / BN, BS / BM), tb, 0, stream>>>(ctxb, wo_t, hid, hs, BS, D, D);

    ln_kernel<<<BS, tb, 0, stream>>>(hid, ln2g, ln2b, x2_b, D);

    // merged w1+w3 with fused SwiGLU epilogue -> hbuf [BS, I]
    gemm2_kernel<6><<<dim3(BS / G2_BM, 8192 / G2_BN), tb, 0, stream>>>(
        x2_b, w13w, hbuf, BS, 8192, D, D);

    // W2: split-K x4, bf16 partials, then reduce + residual
    gemm2_kernel<5><<<dim3(BS / G2_BM, D / G2_BN, 4), tb, 0, stream>>>(
        hbuf, w2w, pker, BS, D, 1024, I);
    reduce4_kernel<<<dim3(BS * D / 4 / 256), tb, 0, stream>>>(pker, hid, out, BS * D / 4);
}